// Round 1
// 1195.519 us; speedup vs baseline: 1.3805x; 1.3805x over previous
//
#include <hip/hip_runtime.h>
#include <math.h>

#define S_LEN 2048
#define DH    64
#define NBH   32     // B*H
#define NIDX  257    // 2*max_rel + 1

typedef _Float16 f16;
typedef f16 f16x8 __attribute__((ext_vector_type(8)));
typedef float f32x4 __attribute__((ext_vector_type(4)));

// ---------------------------------------------------------------------------
// K1: fixed sin-cos table, 257 x 64 fp32  (+ f16 copy for the MFMA qdot)
// ---------------------------------------------------------------------------
__global__ void k_table(float* __restrict__ tab, f16* __restrict__ tabh) {
    int p = blockIdx.x, d = threadIdx.x;
    float div = expf((float)(d & ~1) * (-0.14391156831212787f));
    float ang = (float)p * div;
    float v = (d & 1) ? cosf(ang) : sinf(ang);
    tab[p * DH + d] = v;
    tabh[p * DH + d] = (f16)v;
}

// ---------------------------------------------------------------------------
// K2: elementwise cast K -> f16 (row-major kept)
// ---------------------------------------------------------------------------
__global__ __launch_bounds__(256) void k_cast(const float* __restrict__ src,
                                              f16* __restrict__ dst, int n8) {
    int i = blockIdx.x * blockDim.x + threadIdx.x;
    int stride = gridDim.x * blockDim.x;
    for (; i < n8; i += stride) {
        const float4* p = (const float4*)(src + (size_t)i * 8);
        float4 a = p[0], b = p[1];
        f16x8 v;
        v[0]=(f16)a.x; v[1]=(f16)a.y; v[2]=(f16)a.z; v[3]=(f16)a.w;
        v[4]=(f16)b.x; v[5]=(f16)b.y; v[6]=(f16)b.z; v[7]=(f16)b.w;
        *(f16x8*)(dst + (size_t)i * 8) = v;
    }
}

// ---------------------------------------------------------------------------
// K3: V transpose+cast: VhT[bh][d][k] f16
// ---------------------------------------------------------------------------
__global__ __launch_bounds__(256) void k_vt(const float* __restrict__ V,
                                            f16* __restrict__ VhT) {
    __shared__ float sT[64][65];
    int t = threadIdx.x;
    int k0 = blockIdx.x * 64, bh = blockIdx.y;
#pragma unroll
    for (int i = 0; i < 4; ++i) {
        int c = t + i * 256;            // 0..1023 float4s of the 64x64 tile
        int k = c >> 4, d4 = c & 15;
        float4 v = *(const float4*)(V + ((size_t)bh * S_LEN + k0 + k) * DH + d4 * 4);
        sT[k][d4 * 4 + 0] = v.x; sT[k][d4 * 4 + 1] = v.y;
        sT[k][d4 * 4 + 2] = v.z; sT[k][d4 * 4 + 3] = v.w;
    }
    __syncthreads();
    int d = t >> 2, kq = t & 3;
    f16 buf[16];
#pragma unroll
    for (int i = 0; i < 16; ++i) buf[i] = (f16)sT[kq * 16 + i][d];
    f16* dst = VhT + ((size_t)bh * DH + d) * S_LEN + k0 + kq * 16;
    *(f16x8*)dst = *(f16x8*)&buf[0];
    *(f16x8*)(dst + 8) = *(f16x8*)&buf[8];
}

// ---------------------------------------------------------------------------
// K4: qdAh[bh][q][i] = (f16) dot(Q[bh,q,:], table[i,:])  -- via MFMA.
// This is a [65536 x 64] x [257 x 64]^T matmul; the old scalar-fp32 version
// was dependency-latency bound (497us, VALUBusy 13%, 1% HBM). Each wave
// computes a 16-row x 272-col strip: 17 n-tiles x 2 K-steps of 16x16x32.
// Operand layouts identical to k_flash's QK^T (table rows == K rows).
// ---------------------------------------------------------------------------
__global__ __launch_bounds__(256) void k_qdot(const float* __restrict__ Q,
                                              const f16* __restrict__ tabh,
                                              f16* __restrict__ qdAh) {
    int t = threadIdx.x, w = t >> 6, lane = t & 63;
    int quad = lane >> 4, l15 = lane & 15;
    int bh = blockIdx.y;
    int rbase = blockIdx.x * 64 + w * 16;

    // A-fragment: 16 q-rows, K=64 (fp32 -> f16 cast in-register)
    f16x8 qa[2];
    const float* qrow = Q + ((size_t)bh * S_LEN + rbase + l15) * DH;
#pragma unroll
    for (int s = 0; s < 2; ++s) {
        const float4* p4 = (const float4*)(qrow + s * 32 + quad * 8);
        float4 x = p4[0], y = p4[1];
        f16x8 v;
        v[0]=(f16)x.x; v[1]=(f16)x.y; v[2]=(f16)x.z; v[3]=(f16)x.w;
        v[4]=(f16)y.x; v[5]=(f16)y.y; v[6]=(f16)y.z; v[7]=(f16)y.w;
        qa[s] = v;
    }

    size_t obase = ((size_t)bh * S_LEN + rbase + quad * 4) * NIDX;
#pragma unroll
    for (int nt = 0; nt < 17; ++nt) {
        int col = nt * 16 + l15;
        int cc = col > 256 ? 256 : col;        // clamp the B-frag read (pad tile)
        f32x4 acc = (f32x4){0.f, 0.f, 0.f, 0.f};
#pragma unroll
        for (int s = 0; s < 2; ++s) {
            f16x8 tb = *(const f16x8*)(tabh + (size_t)cc * DH + s * 32 + quad * 8);
            acc = __builtin_amdgcn_mfma_f32_16x16x32_f16(qa[s], tb, acc, 0, 0, 0);
        }
        if (col < NIDX) {
#pragma unroll
            for (int reg = 0; reg < 4; ++reg)
                qdAh[obase + (size_t)reg * NIDX + col] = (f16)acc[reg];
        }
    }
}

// ---------------------------------------------------------------------------
// K5: MFMA flash. Block p handles q-tiles {p, 31-p} (uniform work pairing).
// Wave w owns q-rows [q0+w*16, +16). No __syncthreads in the k-loop: B-frags
// come straight from global f16 (L1/L2-warm); P round-trips through a
// per-wave-private LDS strip for the C->A relayout.
// ---------------------------------------------------------------------------
__global__ __launch_bounds__(256) void k_flash(const float* __restrict__ Q,
                                               const f16* __restrict__ Kh,
                                               const f16* __restrict__ VhT,
                                               const f16* __restrict__ qdAh,
                                               const int* __restrict__ pdir,
                                               float* __restrict__ out,
                                               float* __restrict__ invL) {
    __shared__ f16 pt[64][72];
    int t = threadIdx.x, w = t >> 6, lane = t & 63;
    int quad = lane >> 4, l15 = lane & 15;
    int bh = blockIdx.y;
    int causal = (*pdir) != 0;
    const f16* KhB = Kh + (size_t)bh * S_LEN * DH;
    const f16* VtB = VhT + (size_t)bh * DH * S_LEN;

    for (int qsel = 0; qsel < 2; ++qsel) {
        int qb = qsel ? (31 - (int)blockIdx.x) : (int)blockIdx.x;
        int q0 = qb * 64;
        int rbase = q0 + w * 16;

        f16x8 qa[2];
        {
            const float* qrow = Q + ((size_t)bh * S_LEN + rbase + l15) * DH;
#pragma unroll
            for (int s = 0; s < 2; ++s) {
                const float4* p4 = (const float4*)(qrow + s * 32 + quad * 8);
                float4 x = p4[0], y = p4[1];
                f16x8 v;
                v[0]=(f16)x.x; v[1]=(f16)x.y; v[2]=(f16)x.z; v[3]=(f16)x.w;
                v[4]=(f16)y.x; v[5]=(f16)y.y; v[6]=(f16)y.z; v[7]=(f16)y.w;
                qa[s] = v;
            }
        }
        int rows[4];
        const f16* qdrow[4];
#pragma unroll
        for (int reg = 0; reg < 4; ++reg) {
            rows[reg] = rbase + quad * 4 + reg;
            qdrow[reg] = qdAh + ((size_t)bh * S_LEN + rows[reg]) * NIDX;
        }
        f32x4 oacc[4];
#pragma unroll
        for (int n = 0; n < 4; ++n) oacc[n] = (f32x4){0.f, 0.f, 0.f, 0.f};
        float rsum[4] = {0.f, 0.f, 0.f, 0.f};

        int kend = causal ? qb : 31;
        for (int kt = 0; kt <= kend; ++kt) {
            int kc0 = kt * 64;
            f32x4 sfr[4];
#pragma unroll
            for (int n = 0; n < 4; ++n) {
                f32x4 acc = (f32x4){0.f, 0.f, 0.f, 0.f};
#pragma unroll
                for (int s = 0; s < 2; ++s) {
                    f16x8 kb = *(const f16x8*)(KhB + (size_t)(kc0 + n * 16 + l15) * DH + s * 32 + quad * 8);
                    acc = __builtin_amdgcn_mfma_f32_16x16x32_f16(qa[s], kb, acc, 0, 0, 0);
                }
                sfr[n] = acc;
            }
#pragma unroll
            for (int n = 0; n < 4; ++n) {
                int col = kc0 + n * 16 + l15;
#pragma unroll
                for (int reg = 0; reg < 4; ++reg) {
                    int dist = col - rows[reg];
                    float p;
                    if (causal && dist > 0) {
                        p = 0.f;
                    } else {
                        int idx = dist < -128 ? 0 : (dist > 128 ? 256 : dist + 128);
                        float b = (float)qdrow[reg][idx];
                        p = __expf((sfr[n][reg] + b) * 0.125f);
                    }
                    rsum[reg] += p;
                    pt[w * 16 + quad * 4 + reg][n * 16 + l15] = (f16)p;
                }
            }
#pragma unroll
            for (int s = 0; s < 2; ++s) {
                f16x8 pa = *(const f16x8*)&pt[w * 16 + l15][s * 32 + quad * 8];
#pragma unroll
                for (int n = 0; n < 4; ++n) {
                    f16x8 vb = *(const f16x8*)(VtB + (size_t)(n * 16 + l15) * S_LEN + kc0 + s * 32 + quad * 8);
                    oacc[n] = __builtin_amdgcn_mfma_f32_16x16x32_f16(pa, vb, oacc[n], 0, 0, 0);
                }
            }
        }

        float inv[4];
#pragma unroll
        for (int reg = 0; reg < 4; ++reg) {
            float v = rsum[reg];
            v += __shfl_xor(v, 1, 64);
            v += __shfl_xor(v, 2, 64);
            v += __shfl_xor(v, 4, 64);
            v += __shfl_xor(v, 8, 64);
            inv[reg] = 1.0f / v;
            if (l15 == 0) invL[(size_t)bh * S_LEN + rows[reg]] = inv[reg];
        }
#pragma unroll
        for (int n = 0; n < 4; ++n)
#pragma unroll
            for (int reg = 0; reg < 4; ++reg)
                out[((size_t)bh * S_LEN + rows[reg]) * DH + n * 16 + l15] = oacc[n][reg] * inv[reg];
    }
}

// ---------------------------------------------------------------------------
// K6: recompute scores via MFMA, write normalized p_attn + zero upper tiles.
// ---------------------------------------------------------------------------
__global__ __launch_bounds__(256) void k_pwrite(const float* __restrict__ Q,
                                                const f16* __restrict__ Kh,
                                                const f16* __restrict__ qdAh,
                                                const float* __restrict__ invL,
                                                const int* __restrict__ pdir,
                                                float* __restrict__ P) {
    int t = threadIdx.x, w = t >> 6, lane = t & 63;
    int quad = lane >> 4, l15 = lane & 15;
    int bh = blockIdx.y;
    int causal = (*pdir) != 0;
    const f16* KhB = Kh + (size_t)bh * S_LEN * DH;
    float* Pq = P + (size_t)bh * S_LEN * S_LEN;

    for (int qsel = 0; qsel < 2; ++qsel) {
        int qb = qsel ? (31 - (int)blockIdx.x) : (int)blockIdx.x;
        int q0 = qb * 64;
        int rbase = q0 + w * 16;

        f16x8 qa[2];
        {
            const float* qrow = Q + ((size_t)bh * S_LEN + rbase + l15) * DH;
#pragma unroll
            for (int s = 0; s < 2; ++s) {
                const float4* p4 = (const float4*)(qrow + s * 32 + quad * 8);
                float4 x = p4[0], y = p4[1];
                f16x8 v;
                v[0]=(f16)x.x; v[1]=(f16)x.y; v[2]=(f16)x.z; v[3]=(f16)x.w;
                v[4]=(f16)y.x; v[5]=(f16)y.y; v[6]=(f16)y.z; v[7]=(f16)y.w;
                qa[s] = v;
            }
        }
        int rows[4];
        const f16* qdrow[4];
        float inv[4];
#pragma unroll
        for (int reg = 0; reg < 4; ++reg) {
            rows[reg] = rbase + quad * 4 + reg;
            qdrow[reg] = qdAh + ((size_t)bh * S_LEN + rows[reg]) * NIDX;
            inv[reg] = invL[(size_t)bh * S_LEN + rows[reg]];
        }

        for (int kt = 0; kt < 32; ++kt) {
            int kc0 = kt * 64;
            if (!causal || kt <= qb) {
                f32x4 sfr[4];
#pragma unroll
                for (int n = 0; n < 4; ++n) {
                    f32x4 acc = (f32x4){0.f, 0.f, 0.f, 0.f};
#pragma unroll
                    for (int s = 0; s < 2; ++s) {
                        f16x8 kb = *(const f16x8*)(KhB + (size_t)(kc0 + n * 16 + l15) * DH + s * 32 + quad * 8);
                        acc = __builtin_amdgcn_mfma_f32_16x16x32_f16(qa[s], kb, acc, 0, 0, 0);
                    }
                    sfr[n] = acc;
                }
#pragma unroll
                for (int n = 0; n < 4; ++n) {
                    int col = kc0 + n * 16 + l15;
#pragma unroll
                    for (int reg = 0; reg < 4; ++reg) {
                        int dist = col - rows[reg];
                        float p;
                        if (causal && dist > 0) {
                            p = 0.f;
                        } else {
                            int idx = dist < -128 ? 0 : (dist > 128 ? 256 : dist + 128);
                            float b = (float)qdrow[reg][idx];
                            p = __expf((sfr[n][reg] + b) * 0.125f) * inv[reg];
                        }
                        Pq[(size_t)rows[reg] * S_LEN + col] = p;
                    }
                }
            } else {
                float4 z = make_float4(0.f, 0.f, 0.f, 0.f);
#pragma unroll
                for (int e = 0; e < 4; ++e) {
                    int idx = t + e * 256;
                    int rr = idx >> 4, c4 = idx & 15;
                    *(float4*)&Pq[(size_t)(q0 + rr) * S_LEN + kc0 + c4 * 4] = z;
                }
            }
        }
    }
}

// ---------------------------------------------------------------------------
// K7: add the P·R_v band term to out (unchanged from round 1; verified).
// ---------------------------------------------------------------------------
__global__ __launch_bounds__(256) void k_relv(const float* __restrict__ P,
                                              const float* __restrict__ tab,
                                              const int* __restrict__ pdir,
                                              float* __restrict__ out) {
    int wave = threadIdx.x >> 6, lane = threadIdx.x & 63;   // lane = d
    int q  = blockIdx.x * 4 + wave;
    int bh = blockIdx.y;
    int causal = (*pdir) != 0;
    const float* Prow = P + ((size_t)bh * S_LEN + q) * S_LEN;
    float acc = 0.f;
    if (causal) {
        int k0 = q - 127; if (k0 < 0) k0 = 0;
        int n = q - k0 + 1;
        float p1 = (lane < n) ? Prow[k0 + lane] : 0.f;
        float p2 = (lane + 64 < n) ? Prow[k0 + lane + 64] : 0.f;
        float ts = p1 + p2;
#pragma unroll
        for (int m = 32; m >= 1; m >>= 1) ts += __shfl_xor(ts, m, 64);
        float w0 = 1.0f - ts;
        int idx0 = k0 - q + 128;
        acc = w0 * tab[lane];
        int n1 = n < 64 ? n : 64;
        for (int j = 0; j < n1; ++j) {
            float pj = __shfl(p1, j, 64);
            acc += pj * tab[(size_t)(idx0 + j) * DH + lane];
        }
        for (int j = 64; j < n; ++j) {
            float pj = __shfl(p2, j - 64, 64);
            acc += pj * tab[(size_t)(idx0 + j) * DH + lane];
        }
    } else {
        for (int kc = 0; kc < S_LEN; kc += 64) {
            float pv = Prow[kc + lane];
            for (int j = 0; j < 64; ++j) {
                float pj = __shfl(pv, j, 64);
                int dist = kc + j - q;
                int idx = dist < -128 ? 0 : (dist > 128 ? 256 : dist + 128);
                acc += pj * tab[(size_t)idx * DH + lane];
            }
        }
    }
    out[((size_t)bh * S_LEN + q) * DH + lane] += acc;
}

// ---------------------------------------------------------------------------
extern "C" void kernel_launch(void* const* d_in, const int* in_sizes, int n_in,
                              void* d_out, int out_size, void* d_ws, size_t ws_size,
                              hipStream_t stream) {
    const float* Q = (const float*)d_in[0];
    const float* K = (const float*)d_in[1];
    const float* V = (const float*)d_in[2];
    const int* dir = (const int*)d_in[3];

    float* out = (float*)d_out;                            // [32,2048,64]
    float* P   = out + (size_t)NBH * S_LEN * DH;           // [32,2048,2048]

    char* ws = (char*)d_ws;
    float* tab  = (float*)ws;                              // 65,792 B
    float* invL = (float*)(ws + 65792);                    // 262,144 B
    f16*   qdAh = (f16*)(ws + 327936);                     // 33,685,504 B
    f16*   Kh   = (f16*)(ws + 34013440);                   // 8,388,608 B
    f16*   VhT  = (f16*)(ws + 42402048);                   // 8,388,608 B

    // f16 table lives transiently at the head of the P region: consumed only
    // by k_qdot, and k_pwrite fully overwrites P afterwards. No ws growth.
    f16* tabh = (f16*)P;                                   // 32,896 B

    k_table<<<dim3(NIDX), dim3(DH), 0, stream>>>(tab, tabh);
    k_cast<<<dim3(1024), dim3(256), 0, stream>>>(K, Kh, NBH * S_LEN * DH / 8);
    k_vt<<<dim3(S_LEN / 64, NBH), dim3(256), 0, stream>>>(V, VhT);
    k_qdot<<<dim3(S_LEN / 64, NBH), dim3(256), 0, stream>>>(Q, tabh, qdAh);
    k_flash<<<dim3(16, NBH), dim3(256), 0, stream>>>(Q, Kh, VhT, qdAh, dir, out, invL);
    k_pwrite<<<dim3(16, NBH), dim3(256), 0, stream>>>(Q, Kh, qdAh, invL, dir, P);
    k_relv<<<dim3(S_LEN / 4, NBH), dim3(256), 0, stream>>>(P, tab, dir, out);
}

// Round 3
// 949.714 us; speedup vs baseline: 1.7378x; 1.2588x over previous
//
#include <hip/hip_runtime.h>
#include <math.h>

#define S_LEN 2048
#define DH    64
#define NBH   32     // B*H
#define NIDX  257    // 2*max_rel + 1

typedef _Float16 f16;
typedef f16 f16x8 __attribute__((ext_vector_type(8)));
typedef float f32x4 __attribute__((ext_vector_type(4)));

// ---------------------------------------------------------------------------
// K1: fixed sin-cos table, 257 x 64 fp32 (+ f16 copy for the MFMA qdot)
// ---------------------------------------------------------------------------
__global__ void k_table(float* __restrict__ tab, f16* __restrict__ tabh) {
    int p = blockIdx.x, d = threadIdx.x;
    float div = expf((float)(d & ~1) * (-0.14391156831212787f));
    float ang = (float)p * div;
    float v = (d & 1) ? cosf(ang) : sinf(ang);
    tab[p * DH + d] = v;
    tabh[p * DH + d] = (f16)v;
}

// ---------------------------------------------------------------------------
// K2: elementwise cast K -> f16 (row-major kept)
// ---------------------------------------------------------------------------
__global__ __launch_bounds__(256) void k_cast(const float* __restrict__ src,
                                              f16* __restrict__ dst, int n8) {
    int i = blockIdx.x * blockDim.x + threadIdx.x;
    int stride = gridDim.x * blockDim.x;
    for (; i < n8; i += stride) {
        const float4* p = (const float4*)(src + (size_t)i * 8);
        float4 a = p[0], b = p[1];
        f16x8 v;
        v[0]=(f16)a.x; v[1]=(f16)a.y; v[2]=(f16)a.z; v[3]=(f16)a.w;
        v[4]=(f16)b.x; v[5]=(f16)b.y; v[6]=(f16)b.z; v[7]=(f16)b.w;
        *(f16x8*)(dst + (size_t)i * 8) = v;
    }
}

// ---------------------------------------------------------------------------
// K3: V transpose+cast: VhT[bh][d][k] f16
// ---------------------------------------------------------------------------
__global__ __launch_bounds__(256) void k_vt(const float* __restrict__ V,
                                            f16* __restrict__ VhT) {
    __shared__ float sT[64][65];
    int t = threadIdx.x;
    int k0 = blockIdx.x * 64, bh = blockIdx.y;
#pragma unroll
    for (int i = 0; i < 4; ++i) {
        int c = t + i * 256;            // 0..1023 float4s of the 64x64 tile
        int k = c >> 4, d4 = c & 15;
        float4 v = *(const float4*)(V + ((size_t)bh * S_LEN + k0 + k) * DH + d4 * 4);
        sT[k][d4 * 4 + 0] = v.x; sT[k][d4 * 4 + 1] = v.y;
        sT[k][d4 * 4 + 2] = v.z; sT[k][d4 * 4 + 3] = v.w;
    }
    __syncthreads();
    int d = t >> 2, kq = t & 3;
    f16 buf[16];
#pragma unroll
    for (int i = 0; i < 16; ++i) buf[i] = (f16)sT[kq * 16 + i][d];
    f16* dst = VhT + ((size_t)bh * DH + d) * S_LEN + k0 + kq * 16;
    *(f16x8*)dst = *(f16x8*)&buf[0];
    *(f16x8*)(dst + 8) = *(f16x8*)&buf[8];
}

// ---------------------------------------------------------------------------
// K4: qdAh[bh][q][i] = (f16) dot(Q[bh,q,:], table[i,:])  -- via MFMA.
// ---------------------------------------------------------------------------
__global__ __launch_bounds__(256) void k_qdot(const float* __restrict__ Q,
                                              const f16* __restrict__ tabh,
                                              f16* __restrict__ qdAh) {
    int t = threadIdx.x, w = t >> 6, lane = t & 63;
    int quad = lane >> 4, l15 = lane & 15;
    int bh = blockIdx.y;
    int rbase = blockIdx.x * 64 + w * 16;

    f16x8 qa[2];
    const float* qrow = Q + ((size_t)bh * S_LEN + rbase + l15) * DH;
#pragma unroll
    for (int s = 0; s < 2; ++s) {
        const float4* p4 = (const float4*)(qrow + s * 32 + quad * 8);
        float4 x = p4[0], y = p4[1];
        f16x8 v;
        v[0]=(f16)x.x; v[1]=(f16)x.y; v[2]=(f16)x.z; v[3]=(f16)x.w;
        v[4]=(f16)y.x; v[5]=(f16)y.y; v[6]=(f16)y.z; v[7]=(f16)y.w;
        qa[s] = v;
    }

    size_t obase = ((size_t)bh * S_LEN + rbase + quad * 4) * NIDX;
#pragma unroll
    for (int nt = 0; nt < 17; ++nt) {
        int col = nt * 16 + l15;
        int cc = col > 256 ? 256 : col;        // clamp the B-frag read (pad tile)
        f32x4 acc = (f32x4){0.f, 0.f, 0.f, 0.f};
#pragma unroll
        for (int s = 0; s < 2; ++s) {
            f16x8 tb = *(const f16x8*)(tabh + (size_t)cc * DH + s * 32 + quad * 8);
            acc = __builtin_amdgcn_mfma_f32_16x16x32_f16(qa[s], tb, acc, 0, 0, 0);
        }
        if (col < NIDX) {
#pragma unroll
            for (int reg = 0; reg < 4; ++reg)
                qdAh[obase + (size_t)reg * NIDX + col] = (f16)acc[reg];
        }
    }
}

// ---------------------------------------------------------------------------
// K5: MFMA flash. ALSO stores the unnormalized p tile as packed f16 into the
// upper 4KB of each P row's 8KB slot (row q fp32 at Pq+q*2048; its f16 copy
// at byte offset 4096 + 2*col). Diag tile stores exact zeros past the
// diagonal. invL stores the RAW row sum (consumers rcp it).
// ---------------------------------------------------------------------------
__global__ __launch_bounds__(256) void k_flash(const float* __restrict__ Q,
                                               const f16* __restrict__ Kh,
                                               const f16* __restrict__ VhT,
                                               const f16* __restrict__ qdAh,
                                               const int* __restrict__ pdir,
                                               float* __restrict__ out,
                                               float* __restrict__ invL,
                                               float* __restrict__ P) {
    __shared__ f16 pt[64][72];
    int t = threadIdx.x, w = t >> 6, lane = t & 63;
    int quad = lane >> 4, l15 = lane & 15;
    int bh = blockIdx.y;
    int causal = (*pdir) != 0;
    const f16* KhB = Kh + (size_t)bh * S_LEN * DH;
    const f16* VtB = VhT + (size_t)bh * DH * S_LEN;
    float* Pq = P + (size_t)bh * S_LEN * S_LEN;

    for (int qsel = 0; qsel < 2; ++qsel) {
        int qb = qsel ? (31 - (int)blockIdx.x) : (int)blockIdx.x;
        int q0 = qb * 64;
        int rbase = q0 + w * 16;

        f16x8 qa[2];
        {
            const float* qrow = Q + ((size_t)bh * S_LEN + rbase + l15) * DH;
#pragma unroll
            for (int s = 0; s < 2; ++s) {
                const float4* p4 = (const float4*)(qrow + s * 32 + quad * 8);
                float4 x = p4[0], y = p4[1];
                f16x8 v;
                v[0]=(f16)x.x; v[1]=(f16)x.y; v[2]=(f16)x.z; v[3]=(f16)x.w;
                v[4]=(f16)y.x; v[5]=(f16)y.y; v[6]=(f16)y.z; v[7]=(f16)y.w;
                qa[s] = v;
            }
        }
        int rows[4];
        const f16* qdrow[4];
#pragma unroll
        for (int reg = 0; reg < 4; ++reg) {
            rows[reg] = rbase + quad * 4 + reg;
            qdrow[reg] = qdAh + ((size_t)bh * S_LEN + rows[reg]) * NIDX;
        }
        f32x4 oacc[4];
#pragma unroll
        for (int n = 0; n < 4; ++n) oacc[n] = (f32x4){0.f, 0.f, 0.f, 0.f};
        float rsum[4] = {0.f, 0.f, 0.f, 0.f};

        int kend = causal ? qb : 31;
        for (int kt = 0; kt <= kend; ++kt) {
            int kc0 = kt * 64;
            f32x4 sfr[4];
#pragma unroll
            for (int n = 0; n < 4; ++n) {
                f32x4 acc = (f32x4){0.f, 0.f, 0.f, 0.f};
#pragma unroll
                for (int s = 0; s < 2; ++s) {
                    f16x8 kb = *(const f16x8*)(KhB + (size_t)(kc0 + n * 16 + l15) * DH + s * 32 + quad * 8);
                    acc = __builtin_amdgcn_mfma_f32_16x16x32_f16(qa[s], kb, acc, 0, 0, 0);
                }
                sfr[n] = acc;
            }
#pragma unroll
            for (int n = 0; n < 4; ++n) {
                int col = kc0 + n * 16 + l15;
#pragma unroll
                for (int reg = 0; reg < 4; ++reg) {
                    int dist = col - rows[reg];
                    float p;
                    if (causal && dist > 0) {
                        p = 0.f;
                    } else {
                        int idx = dist < -128 ? 0 : (dist > 128 ? 256 : dist + 128);
                        float b = (float)qdrow[reg][idx];
                        p = __expf((sfr[n][reg] + b) * 0.125f);
                    }
                    rsum[reg] += p;
                    pt[w * 16 + quad * 4 + reg][n * 16 + l15] = (f16)p;
                }
            }
#pragma unroll
            for (int s = 0; s < 2; ++s) {
                f16x8 pa = *(const f16x8*)&pt[w * 16 + l15][s * 32 + quad * 8];
                // packed f16 store of the unnormalized p band
                *(f16x8*)((char*)(Pq + (size_t)(rbase + l15) * S_LEN) + 4096
                          + 2 * (kc0 + s * 32 + quad * 8)) = pa;
#pragma unroll
                for (int n = 0; n < 4; ++n) {
                    f16x8 vb = *(const f16x8*)(VtB + (size_t)(n * 16 + l15) * S_LEN + kc0 + s * 32 + quad * 8);
                    oacc[n] = __builtin_amdgcn_mfma_f32_16x16x32_f16(pa, vb, oacc[n], 0, 0, 0);
                }
            }
        }

        float inv[4];
#pragma unroll
        for (int reg = 0; reg < 4; ++reg) {
            float v = rsum[reg];
            v += __shfl_xor(v, 1, 64);
            v += __shfl_xor(v, 2, 64);
            v += __shfl_xor(v, 4, 64);
            v += __shfl_xor(v, 8, 64);
            inv[reg] = 1.0f / v;
            if (l15 == 0) invL[(size_t)bh * S_LEN + rows[reg]] = v;   // raw sum
        }
#pragma unroll
        for (int n = 0; n < 4; ++n)
#pragma unroll
            for (int reg = 0; reg < 4; ++reg)
                out[((size_t)bh * S_LEN + rows[reg]) * DH + n * 16 + l15] = oacc[n][reg] * inv[reg];
    }
}

// ---------------------------------------------------------------------------
// K6: rel-v band term via MFMA. Causal only (early-exit otherwise).
// out_rel[q,d] = inv * ( sum_{j=0..159} W[q,j]*tab[j][d] + tail*tab[0][d] )
// with W[q,j] = p16[q, q+j-128] read diagonally from an LDS band stage,
// tail = rowsum - bandsum (the <-128 clamp mass). The transposed f16 table
// is built in LDS from fp32 tab (no extra workspace). Runs BEFORE k_pnorm.
// ---------------------------------------------------------------------------
__global__ __launch_bounds__(256) void k_relv2(const float* __restrict__ tab,
                                               const float* __restrict__ invL,
                                               const int* __restrict__ pdir,
                                               const float* __restrict__ P,
                                               float* __restrict__ out) {
    if ((*pdir) == 0) return;
    __shared__ f16 band[64][224];
    __shared__ f16 sT[64][168];     // sT[d][j] = tab[j][d] (j<=128), 0 beyond
    int t = threadIdx.x, w = t >> 6, lane = t & 63;
    int quad = lane >> 4, l15 = lane & 15;
    int q0 = blockIdx.x * 64, bh = blockIdx.y;
    const float* Pb = P + (size_t)bh * S_LEN * S_LEN;

    // stage transposed table (coalesced on d; tab is L2-resident)
#pragma unroll
    for (int i = 0; i < 40; ++i) {
        int e = t + i * 256;
        int d = e & 63, j = e >> 6;
        sT[d][j] = (j <= 128) ? (f16)tab[(size_t)j * DH + d] : (f16)0.f;
    }
    // stage: band[r][c] = p16[q0+r][q0-128+c] for c<192 & col>=0, else 0
    {
        int r = t >> 2, part = t & 3;
#pragma unroll
        for (int ch = 0; ch < 7; ++ch) {
            int c = part * 56 + ch * 8;
            int col = q0 - 128 + c;
            f16x8 v;
#pragma unroll
            for (int e = 0; e < 8; ++e) v[e] = (f16)0.f;
            if (c < 192 && col >= 0)
                v = *(const f16x8*)((const char*)(Pb + (size_t)(q0 + r) * S_LEN) + 4096 + 2 * col);
            *(f16x8*)&band[r][c] = v;
        }
    }
    __syncthreads();

    int lr = w * 16 + l15;                    // A-frag row (local)
    f32x4 racc[4];
#pragma unroll
    for (int n = 0; n < 4; ++n) racc[n] = (f32x4){0.f, 0.f, 0.f, 0.f};
#pragma unroll
    for (int js = 0; js < 160; js += 32) {
        f16 a_[8];
#pragma unroll
        for (int jj = 0; jj < 8; ++jj) a_[jj] = band[lr][lr + js + quad * 8 + jj];
        f16x8 af = *(f16x8*)a_;
#pragma unroll
        for (int n = 0; n < 4; ++n) {
            f16x8 bf = *(const f16x8*)&sT[n * 16 + l15][js + quad * 8];
            racc[n] = __builtin_amdgcn_mfma_f32_16x16x32_f16(af, bf, racc[n], 0, 0, 0);
        }
    }

    // bandsum (j residues per quad; j>128 entries are zero) -> tail weight
    float bs = 0.f;
#pragma unroll
    for (int i = 0; i <= 32; ++i) bs += (float)band[lr][lr + quad + 4 * i];
    bs += __shfl_xor(bs, 16, 64);
    bs += __shfl_xor(bs, 32, 64);

    float rs = invL[(size_t)bh * S_LEN + q0 + lr];
    float inv_l = 1.0f / rs;
    float tailw = (rs - bs) * inv_l;

    float invm[4], tm[4];
#pragma unroll
    for (int reg = 0; reg < 4; ++reg) {
        int m = quad * 4 + reg;
        invm[reg] = __shfl(inv_l, m, 64);
        tm[reg]   = __shfl(tailw, m, 64);
    }
#pragma unroll
    for (int n = 0; n < 4; ++n) {
        float t0 = tab[n * 16 + l15];         // tab[0][d]
#pragma unroll
        for (int reg = 0; reg < 4; ++reg) {
            size_t o = ((size_t)bh * S_LEN + q0 + w * 16 + quad * 4 + reg) * DH + n * 16 + l15;
            out[o] += racc[n][reg] * invm[reg] + tm[reg] * t0;
        }
    }
}

// ---------------------------------------------------------------------------
// K7: normalize P rows. Pure bandwidth: read packed p16 (upper half of each
// row slot), scale by 1/rowsum, write full fp32 row. The s_waitcnt guards
// the in-row aliasing (stores to cols>=1024 overwrite the p16 source).
// ---------------------------------------------------------------------------
__global__ __launch_bounds__(256) void k_pnorm(const float* __restrict__ invL,
                                               const int* __restrict__ pdir,
                                               float* __restrict__ P) {
    int w = threadIdx.x >> 6, lane = threadIdx.x & 63;
    int row = blockIdx.x * 4 + w, bh = blockIdx.y;
    int causal = (*pdir) != 0;
    float inv = 1.0f / invL[(size_t)bh * S_LEN + row];
    float* Prow = P + ((size_t)bh * S_LEN + row) * S_LEN;
    const f16* p16 = (const f16*)((const char*)Prow + 4096);
    f16x8 v[4];
#pragma unroll
    for (int i = 0; i < 4; ++i) {
        int c0 = lane * 8 + i * 512;
        f16x8 z;
#pragma unroll
        for (int e = 0; e < 8; ++e) z[e] = (f16)0.f;
        v[i] = (!causal || c0 <= row) ? *(const f16x8*)(p16 + c0) : z;
    }
    asm volatile("s_waitcnt vmcnt(0)" ::: "memory");
#pragma unroll
    for (int i = 0; i < 4; ++i) {
        int c0 = lane * 8 + i * 512;
        float4 o0, o1;
        o0.x = (float)v[i][0] * inv; o0.y = (float)v[i][1] * inv;
        o0.z = (float)v[i][2] * inv; o0.w = (float)v[i][3] * inv;
        o1.x = (float)v[i][4] * inv; o1.y = (float)v[i][5] * inv;
        o1.z = (float)v[i][6] * inv; o1.w = (float)v[i][7] * inv;
        *(float4*)(Prow + c0) = o0;
        *(float4*)(Prow + c0 + 4) = o1;
    }
}

// ---------------------------------------------------------------------------
// K8: non-causal P.R_v fallback only (causal handled by k_relv2).
// ---------------------------------------------------------------------------
__global__ __launch_bounds__(256) void k_relv(const float* __restrict__ P,
                                              const float* __restrict__ tab,
                                              const int* __restrict__ pdir,
                                              float* __restrict__ out) {
    if ((*pdir) != 0) return;
    int wave = threadIdx.x >> 6, lane = threadIdx.x & 63;   // lane = d
    int q  = blockIdx.x * 4 + wave;
    int bh = blockIdx.y;
    const float* Prow = P + ((size_t)bh * S_LEN + q) * S_LEN;
    float acc = 0.f;
    for (int kc = 0; kc < S_LEN; kc += 64) {
        float pv = Prow[kc + lane];
        for (int j = 0; j < 64; ++j) {
            float pj = __shfl(pv, j, 64);
            int dist = kc + j - q;
            int idx = dist < -128 ? 0 : (dist > 128 ? 256 : dist + 128);
            acc += pj * tab[(size_t)idx * DH + lane];
        }
    }
    out[((size_t)bh * S_LEN + q) * DH + lane] += acc;
}

// ---------------------------------------------------------------------------
extern "C" void kernel_launch(void* const* d_in, const int* in_sizes, int n_in,
                              void* d_out, int out_size, void* d_ws, size_t ws_size,
                              hipStream_t stream) {
    const float* Q = (const float*)d_in[0];
    const float* K = (const float*)d_in[1];
    const float* V = (const float*)d_in[2];
    const int* dir = (const int*)d_in[3];

    float* out = (float*)d_out;                            // [32,2048,64]
    float* P   = out + (size_t)NBH * S_LEN * DH;           // [32,2048,2048]

    char* ws = (char*)d_ws;
    float* tab  = (float*)ws;                              // 65,792 B
    float* invL = (float*)(ws + 65792);                    // 262,144 B (raw row sums)
    f16*   qdAh = (f16*)(ws + 327936);                     // 33,685,504 B
    f16*   Kh   = (f16*)(ws + 34013440);                   // 8,388,608 B
    f16*   VhT  = (f16*)(ws + 42402048);                   // 8,388,608 B -> 50,790,656 B total (same as round 1)

    // f16 table lives transiently at the head of the P region: consumed only
    // by k_qdot, then overwritten by k_flash's p16 stores / k_pnorm.
    f16* tabh = (f16*)P;                                   // 32,896 B

    k_table<<<dim3(NIDX), dim3(DH), 0, stream>>>(tab, tabh);
    k_cast<<<dim3(1024), dim3(256), 0, stream>>>(K, Kh, NBH * S_LEN * DH / 8);
    k_vt<<<dim3(S_LEN / 64, NBH), dim3(256), 0, stream>>>(V, VhT);
    k_qdot<<<dim3(S_LEN / 64, NBH), dim3(256), 0, stream>>>(Q, tabh, qdAh);
    k_flash<<<dim3(16, NBH), dim3(256), 0, stream>>>(Q, Kh, VhT, qdAh, dir, out, invL, P);
    k_relv2<<<dim3(S_LEN / 64, NBH), dim3(256), 0, stream>>>(tab, invL, dir, P, out);
    k_pnorm<<<dim3(S_LEN / 4, NBH), dim3(256), 0, stream>>>(invL, dir, P);
    k_relv<<<dim3(S_LEN / 4, NBH), dim3(256), 0, stream>>>(P, tab, dir, out);
}

// Round 5
// 848.518 us; speedup vs baseline: 1.9451x; 1.1193x over previous
//
#include <hip/hip_runtime.h>
#include <math.h>

#define S_LEN 2048
#define DH    64
#define NBH   32     // B*H
#define NIDX  257    // 2*max_rel + 1

typedef _Float16 f16;
typedef f16 f16x8 __attribute__((ext_vector_type(8)));
typedef float f32x4 __attribute__((ext_vector_type(4)));

// ---------------------------------------------------------------------------
// K1: fixed sin-cos table, 257 x 64 fp32 (+ f16 copy for the MFMA qdot)
// ---------------------------------------------------------------------------
__global__ void k_table(float* __restrict__ tab, f16* __restrict__ tabh) {
    int p = blockIdx.x, d = threadIdx.x;
    float div = expf((float)(d & ~1) * (-0.14391156831212787f));
    float ang = (float)p * div;
    float v = (d & 1) ? cosf(ang) : sinf(ang);
    tab[p * DH + d] = v;
    tabh[p * DH + d] = (f16)v;
}

// ---------------------------------------------------------------------------
// K2: elementwise cast K -> f16 (row-major kept)
// ---------------------------------------------------------------------------
__global__ __launch_bounds__(256) void k_cast(const float* __restrict__ src,
                                              f16* __restrict__ dst, int n8) {
    int i = blockIdx.x * blockDim.x + threadIdx.x;
    int stride = gridDim.x * blockDim.x;
    for (; i < n8; i += stride) {
        const float4* p = (const float4*)(src + (size_t)i * 8);
        float4 a = p[0], b = p[1];
        f16x8 v;
        v[0]=(f16)a.x; v[1]=(f16)a.y; v[2]=(f16)a.z; v[3]=(f16)a.w;
        v[4]=(f16)b.x; v[5]=(f16)b.y; v[6]=(f16)b.z; v[7]=(f16)b.w;
        *(f16x8*)(dst + (size_t)i * 8) = v;
    }
}

// ---------------------------------------------------------------------------
// K3: V transpose+cast: VhT[bh][d][k] f16
// ---------------------------------------------------------------------------
__global__ __launch_bounds__(256) void k_vt(const float* __restrict__ V,
                                            f16* __restrict__ VhT) {
    __shared__ float sT[64][65];
    int t = threadIdx.x;
    int k0 = blockIdx.x * 64, bh = blockIdx.y;
#pragma unroll
    for (int i = 0; i < 4; ++i) {
        int c = t + i * 256;            // 0..1023 float4s of the 64x64 tile
        int k = c >> 4, d4 = c & 15;
        float4 v = *(const float4*)(V + ((size_t)bh * S_LEN + k0 + k) * DH + d4 * 4);
        sT[k][d4 * 4 + 0] = v.x; sT[k][d4 * 4 + 1] = v.y;
        sT[k][d4 * 4 + 2] = v.z; sT[k][d4 * 4 + 3] = v.w;
    }
    __syncthreads();
    int d = t >> 2, kq = t & 3;
    f16 buf[16];
#pragma unroll
    for (int i = 0; i < 16; ++i) buf[i] = (f16)sT[kq * 16 + i][d];
    f16* dst = VhT + ((size_t)bh * DH + d) * S_LEN + k0 + kq * 16;
    *(f16x8*)dst = *(f16x8*)&buf[0];
    *(f16x8*)(dst + 8) = *(f16x8*)&buf[8];
}

// ---------------------------------------------------------------------------
// K4: qdAh[bh][q][i] = (f16) dot(Q[bh,q,:], table[i,:])  -- via MFMA.
// ---------------------------------------------------------------------------
__global__ __launch_bounds__(256) void k_qdot(const float* __restrict__ Q,
                                              const f16* __restrict__ tabh,
                                              f16* __restrict__ qdAh) {
    int t = threadIdx.x, w = t >> 6, lane = t & 63;
    int quad = lane >> 4, l15 = lane & 15;
    int bh = blockIdx.y;
    int rbase = blockIdx.x * 64 + w * 16;

    f16x8 qa[2];
    const float* qrow = Q + ((size_t)bh * S_LEN + rbase + l15) * DH;
#pragma unroll
    for (int s = 0; s < 2; ++s) {
        const float4* p4 = (const float4*)(qrow + s * 32 + quad * 8);
        float4 x = p4[0], y = p4[1];
        f16x8 v;
        v[0]=(f16)x.x; v[1]=(f16)x.y; v[2]=(f16)x.z; v[3]=(f16)x.w;
        v[4]=(f16)y.x; v[5]=(f16)y.y; v[6]=(f16)y.z; v[7]=(f16)y.w;
        qa[s] = v;
    }

    size_t obase = ((size_t)bh * S_LEN + rbase + quad * 4) * NIDX;
#pragma unroll
    for (int nt = 0; nt < 17; ++nt) {
        int col = nt * 16 + l15;
        int cc = col > 256 ? 256 : col;        // clamp the B-frag read (pad tile)
        f32x4 acc = (f32x4){0.f, 0.f, 0.f, 0.f};
#pragma unroll
        for (int s = 0; s < 2; ++s) {
            f16x8 tb = *(const f16x8*)(tabh + (size_t)cc * DH + s * 32 + quad * 8);
            acc = __builtin_amdgcn_mfma_f32_16x16x32_f16(qa[s], tb, acc, 0, 0, 0);
        }
        if (col < NIDX) {
#pragma unroll
            for (int reg = 0; reg < 4; ++reg)
                qdAh[obase + (size_t)reg * NIDX + col] = (f16)acc[reg];
        }
    }
}

// ---------------------------------------------------------------------------
// K5: MFMA flash. One q-tile per block (grid 32x32 -> 4 blocks/CU, 2x the
// waves/SIMD of the old paired layout). Causal balance lifted to the grid
// mapping: under linear round-robin block->CU assignment a CU's 4 blocks are
// (bx, bh+{0,8,16,24}), so qb complement-pairs across bh>>3 rounds make
// every CU's work sum exactly 2*33 tile-units.
// Far-from-diagonal tiles take a constant-bias fast path (idx clamps to 0
// resp. 256 for every element) -> no per-element qdAh gather.
// Stores unnormalized p as packed f16 into the upper 4KB of each P row slot.
// invL stores the RAW row sum.
// ---------------------------------------------------------------------------
__global__ __launch_bounds__(256) void k_flash(const float* __restrict__ Q,
                                               const f16* __restrict__ Kh,
                                               const f16* __restrict__ VhT,
                                               const f16* __restrict__ qdAh,
                                               const int* __restrict__ pdir,
                                               float* __restrict__ out,
                                               float* __restrict__ invL,
                                               float* __restrict__ P) {
    __shared__ f16 pt[64][72];
    int t = threadIdx.x, w = t >> 6, lane = t & 63;
    int quad = lane >> 4, l15 = lane & 15;
    int bh = blockIdx.y;
    int causal = (*pdir) != 0;
    const f16* KhB = Kh + (size_t)bh * S_LEN * DH;
    const f16* VtB = VhT + (size_t)bh * DH * S_LEN;
    float* Pq = P + (size_t)bh * S_LEN * S_LEN;

    // complement-pair qb mapping (bijective per bh)
    int r = bh >> 3;
    int base = (r & 2) ? ((int)blockIdx.x ^ 16) : (int)blockIdx.x;
    int qb = (r & 1) ? (31 - base) : base;
    int q0 = qb * 64;
    int rbase = q0 + w * 16;

    f16x8 qa[2];
    {
        const float* qrow = Q + ((size_t)bh * S_LEN + rbase + l15) * DH;
#pragma unroll
        for (int s = 0; s < 2; ++s) {
            const float4* p4 = (const float4*)(qrow + s * 32 + quad * 8);
            float4 x = p4[0], y = p4[1];
            f16x8 v;
            v[0]=(f16)x.x; v[1]=(f16)x.y; v[2]=(f16)x.z; v[3]=(f16)x.w;
            v[4]=(f16)y.x; v[5]=(f16)y.y; v[6]=(f16)y.z; v[7]=(f16)y.w;
            qa[s] = v;
        }
    }
    int rows[4];
    const f16* qdrow[4];
    float bb0[4], bb256[4];
#pragma unroll
    for (int reg = 0; reg < 4; ++reg) {
        rows[reg] = rbase + quad * 4 + reg;
        qdrow[reg] = qdAh + ((size_t)bh * S_LEN + rows[reg]) * NIDX;
        bb0[reg]   = (float)qdrow[reg][0];     // dist < -128 clamp bias
        bb256[reg] = (float)qdrow[reg][256];   // dist > 128 clamp bias
    }
    f32x4 oacc[4];
#pragma unroll
    for (int n = 0; n < 4; ++n) oacc[n] = (f32x4){0.f, 0.f, 0.f, 0.f};
    float rsum[4] = {0.f, 0.f, 0.f, 0.f};

    int kend = causal ? qb : 31;
    for (int kt = 0; kt <= kend; ++kt) {
        int kc0 = kt * 64;
        f32x4 sfr[4];
#pragma unroll
        for (int n = 0; n < 4; ++n) {
            f32x4 acc = (f32x4){0.f, 0.f, 0.f, 0.f};
#pragma unroll
            for (int s = 0; s < 2; ++s) {
                f16x8 kb = *(const f16x8*)(KhB + (size_t)(kc0 + n * 16 + l15) * DH + s * 32 + quad * 8);
                acc = __builtin_amdgcn_mfma_f32_16x16x32_f16(qa[s], kb, acc, 0, 0, 0);
            }
            sfr[n] = acc;
        }
        // tile classification (wave-uniform): all-idx-0 / all-idx-256 / general
        int fast = 0;
        if (kc0 + 63 < rbase - 128) fast = 1;
        else if (!causal && kc0 > rbase + 15 + 128) fast = 2;
        if (fast) {
#pragma unroll
            for (int n = 0; n < 4; ++n) {
#pragma unroll
                for (int reg = 0; reg < 4; ++reg) {
                    float b = (fast == 1) ? bb0[reg] : bb256[reg];
                    float p = __expf((sfr[n][reg] + b) * 0.125f);
                    rsum[reg] += p;
                    pt[w * 16 + quad * 4 + reg][n * 16 + l15] = (f16)p;
                }
            }
        } else {
#pragma unroll
            for (int n = 0; n < 4; ++n) {
                int col = kc0 + n * 16 + l15;
#pragma unroll
                for (int reg = 0; reg < 4; ++reg) {
                    int dist = col - rows[reg];
                    float p;
                    if (causal && dist > 0) {
                        p = 0.f;
                    } else {
                        int idx = dist < -128 ? 0 : (dist > 128 ? 256 : dist + 128);
                        float b = (float)qdrow[reg][idx];
                        p = __expf((sfr[n][reg] + b) * 0.125f);
                    }
                    rsum[reg] += p;
                    pt[w * 16 + quad * 4 + reg][n * 16 + l15] = (f16)p;
                }
            }
        }
#pragma unroll
        for (int s = 0; s < 2; ++s) {
            f16x8 pa = *(const f16x8*)&pt[w * 16 + l15][s * 32 + quad * 8];
            // packed f16 store of the unnormalized p band
            *(f16x8*)((char*)(Pq + (size_t)(rbase + l15) * S_LEN) + 4096
                      + 2 * (kc0 + s * 32 + quad * 8)) = pa;
#pragma unroll
            for (int n = 0; n < 4; ++n) {
                f16x8 vb = *(const f16x8*)(VtB + (size_t)(n * 16 + l15) * S_LEN + kc0 + s * 32 + quad * 8);
                oacc[n] = __builtin_amdgcn_mfma_f32_16x16x32_f16(pa, vb, oacc[n], 0, 0, 0);
            }
        }
    }

    float inv[4];
#pragma unroll
    for (int reg = 0; reg < 4; ++reg) {
        float v = rsum[reg];
        v += __shfl_xor(v, 1, 64);
        v += __shfl_xor(v, 2, 64);
        v += __shfl_xor(v, 4, 64);
        v += __shfl_xor(v, 8, 64);
        inv[reg] = 1.0f / v;
        if (l15 == 0) invL[(size_t)bh * S_LEN + rows[reg]] = v;   // raw sum
    }
#pragma unroll
    for (int n = 0; n < 4; ++n)
#pragma unroll
        for (int reg = 0; reg < 4; ++reg)
            out[((size_t)bh * S_LEN + rows[reg]) * DH + n * 16 + l15] = oacc[n][reg] * inv[reg];
}

// ---------------------------------------------------------------------------
// K6: rel-v band term via MFMA. Causal only (early-exit otherwise).
// out_rel[q,d] = inv * ( sum_{j=0..159} W[q,j]*tab[j][d] + tail*tab[0][d] )
// with W[q,j] = p16[q, q+j-128] read diagonally from an LDS band stage,
// tail = rowsum - bandsum (the <-128 clamp mass). The transposed f16 table
// is built in LDS from fp32 tab (no extra workspace). Runs BEFORE k_pnorm.
// ---------------------------------------------------------------------------
__global__ __launch_bounds__(256) void k_relv2(const float* __restrict__ tab,
                                               const float* __restrict__ invL,
                                               const int* __restrict__ pdir,
                                               const float* __restrict__ P,
                                               float* __restrict__ out) {
    if ((*pdir) == 0) return;
    __shared__ f16 band[64][224];
    __shared__ f16 sT[64][168];     // sT[d][j] = tab[j][d] (j<=128), 0 beyond
    int t = threadIdx.x, w = t >> 6, lane = t & 63;
    int quad = lane >> 4, l15 = lane & 15;
    int q0 = blockIdx.x * 64, bh = blockIdx.y;
    const float* Pb = P + (size_t)bh * S_LEN * S_LEN;

    // stage transposed table (coalesced on d; tab is L2-resident)
#pragma unroll
    for (int i = 0; i < 40; ++i) {
        int e = t + i * 256;
        int d = e & 63, j = e >> 6;
        sT[d][j] = (j <= 128) ? (f16)tab[(size_t)j * DH + d] : (f16)0.f;
    }
    // stage: band[r][c] = p16[q0+r][q0-128+c] for c<192 & col>=0, else 0
    {
        int r = t >> 2, part = t & 3;
#pragma unroll
        for (int ch = 0; ch < 7; ++ch) {
            int c = part * 56 + ch * 8;
            int col = q0 - 128 + c;
            f16x8 v;
#pragma unroll
            for (int e = 0; e < 8; ++e) v[e] = (f16)0.f;
            if (c < 192 && col >= 0)
                v = *(const f16x8*)((const char*)(Pb + (size_t)(q0 + r) * S_LEN) + 4096 + 2 * col);
            *(f16x8*)&band[r][c] = v;
        }
    }
    __syncthreads();

    int lr = w * 16 + l15;                    // A-frag row (local)
    f32x4 racc[4];
#pragma unroll
    for (int n = 0; n < 4; ++n) racc[n] = (f32x4){0.f, 0.f, 0.f, 0.f};
#pragma unroll
    for (int js = 0; js < 160; js += 32) {
        f16 a_[8];
#pragma unroll
        for (int jj = 0; jj < 8; ++jj) a_[jj] = band[lr][lr + js + quad * 8 + jj];
        f16x8 af = *(f16x8*)a_;
#pragma unroll
        for (int n = 0; n < 4; ++n) {
            f16x8 bf = *(const f16x8*)&sT[n * 16 + l15][js + quad * 8];
            racc[n] = __builtin_amdgcn_mfma_f32_16x16x32_f16(af, bf, racc[n], 0, 0, 0);
        }
    }

    // bandsum (j residues per quad; j>128 entries are zero) -> tail weight
    float bs = 0.f;
#pragma unroll
    for (int i = 0; i <= 32; ++i) bs += (float)band[lr][lr + quad + 4 * i];
    bs += __shfl_xor(bs, 16, 64);
    bs += __shfl_xor(bs, 32, 64);

    float rs = invL[(size_t)bh * S_LEN + q0 + lr];
    float inv_l = 1.0f / rs;
    float tailw = (rs - bs) * inv_l;

    float invm[4], tm[4];
#pragma unroll
    for (int reg = 0; reg < 4; ++reg) {
        int m = quad * 4 + reg;
        invm[reg] = __shfl(inv_l, m, 64);
        tm[reg]   = __shfl(tailw, m, 64);
    }
#pragma unroll
    for (int n = 0; n < 4; ++n) {
        float t0 = tab[n * 16 + l15];         // tab[0][d]
#pragma unroll
        for (int reg = 0; reg < 4; ++reg) {
            size_t o = ((size_t)bh * S_LEN + q0 + w * 16 + quad * 4 + reg) * DH + n * 16 + l15;
            out[o] += racc[n][reg] * invm[reg] + tm[reg] * t0;
        }
    }
}

// ---------------------------------------------------------------------------
// K7: normalize P rows. Pure bandwidth: read packed p16 (upper half of each
// row slot), scale by 1/rowsum, write full fp32 row. The s_waitcnt guards
// the in-row aliasing (stores to cols>=1024 overwrite the p16 source).
// ---------------------------------------------------------------------------
__global__ __launch_bounds__(256) void k_pnorm(const float* __restrict__ invL,
                                               const int* __restrict__ pdir,
                                               float* __restrict__ P) {
    int w = threadIdx.x >> 6, lane = threadIdx.x & 63;
    int row = blockIdx.x * 4 + w, bh = blockIdx.y;
    int causal = (*pdir) != 0;
    float inv = 1.0f / invL[(size_t)bh * S_LEN + row];
    float* Prow = P + ((size_t)bh * S_LEN + row) * S_LEN;
    const f16* p16 = (const f16*)((const char*)Prow + 4096);
    f16x8 v[4];
#pragma unroll
    for (int i = 0; i < 4; ++i) {
        int c0 = lane * 8 + i * 512;
        f16x8 z;
#pragma unroll
        for (int e = 0; e < 8; ++e) z[e] = (f16)0.f;
        v[i] = (!causal || c0 <= row) ? *(const f16x8*)(p16 + c0) : z;
    }
    asm volatile("s_waitcnt vmcnt(0)" ::: "memory");
#pragma unroll
    for (int i = 0; i < 4; ++i) {
        int c0 = lane * 8 + i * 512;
        float4 o0, o1;
        o0.x = (float)v[i][0] * inv; o0.y = (float)v[i][1] * inv;
        o0.z = (float)v[i][2] * inv; o0.w = (float)v[i][3] * inv;
        o1.x = (float)v[i][4] * inv; o1.y = (float)v[i][5] * inv;
        o1.z = (float)v[i][6] * inv; o1.w = (float)v[i][7] * inv;
        *(float4*)(Prow + c0) = o0;
        *(float4*)(Prow + c0 + 4) = o1;
    }
}

// ---------------------------------------------------------------------------
// K8: non-causal P.R_v fallback only (causal handled by k_relv2).
// ---------------------------------------------------------------------------
__global__ __launch_bounds__(256) void k_relv(const float* __restrict__ P,
                                              const float* __restrict__ tab,
                                              const int* __restrict__ pdir,
                                              float* __restrict__ out) {
    if ((*pdir) != 0) return;
    int wave = threadIdx.x >> 6, lane = threadIdx.x & 63;   // lane = d
    int q  = blockIdx.x * 4 + wave;
    int bh = blockIdx.y;
    const float* Prow = P + ((size_t)bh * S_LEN + q) * S_LEN;
    float acc = 0.f;
    for (int kc = 0; kc < S_LEN; kc += 64) {
        float pv = Prow[kc + lane];
        for (int j = 0; j < 64; ++j) {
            float pj = __shfl(pv, j, 64);
            int dist = kc + j - q;
            int idx = dist < -128 ? 0 : (dist > 128 ? 256 : dist + 128);
            acc += pj * tab[(size_t)idx * DH + lane];
        }
    }
    out[((size_t)bh * S_LEN + q) * DH + lane] += acc;
}

// ---------------------------------------------------------------------------
extern "C" void kernel_launch(void* const* d_in, const int* in_sizes, int n_in,
                              void* d_out, int out_size, void* d_ws, size_t ws_size,
                              hipStream_t stream) {
    const float* Q = (const float*)d_in[0];
    const float* K = (const float*)d_in[1];
    const float* V = (const float*)d_in[2];
    const int* dir = (const int*)d_in[3];

    float* out = (float*)d_out;                            // [32,2048,64]
    float* P   = out + (size_t)NBH * S_LEN * DH;           // [32,2048,2048]

    char* ws = (char*)d_ws;
    float* tab  = (float*)ws;                              // 65,792 B
    float* invL = (float*)(ws + 65792);                    // 262,144 B (raw row sums)
    f16*   qdAh = (f16*)(ws + 327936);                     // 33,685,504 B
    f16*   Kh   = (f16*)(ws + 34013440);                   // 8,388,608 B
    f16*   VhT  = (f16*)(ws + 42402048);                   // 8,388,608 B -> 50,790,656 B total (same as round 1)

    // f16 table lives transiently at the head of the P region: consumed only
    // by k_qdot, then overwritten by k_flash's p16 stores / k_pnorm.
    f16* tabh = (f16*)P;                                   // 32,896 B

    k_table<<<dim3(NIDX), dim3(DH), 0, stream>>>(tab, tabh);
    k_cast<<<dim3(1024), dim3(256), 0, stream>>>(K, Kh, NBH * S_LEN * DH / 8);
    k_vt<<<dim3(S_LEN / 64, NBH), dim3(256), 0, stream>>>(V, VhT);
    k_qdot<<<dim3(S_LEN / 64, NBH), dim3(256), 0, stream>>>(Q, tabh, qdAh);
    k_flash<<<dim3(32, NBH), dim3(256), 0, stream>>>(Q, Kh, VhT, qdAh, dir, out, invL, P);
    k_relv2<<<dim3(S_LEN / 64, NBH), dim3(256), 0, stream>>>(tab, invL, dir, P, out);
    k_pnorm<<<dim3(S_LEN / 4, NBH), dim3(256), 0, stream>>>(invL, dir, P);
    k_relv<<<dim3(S_LEN / 4, NBH), dim3(256), 0, stream>>>(P, tab, dir, out);
}